// Round 1
// baseline (178.739 us; speedup 1.0000x reference)
//
#include <hip/hip_runtime.h>

#define HH 512
#define WW 512
#define HO 502
#define WO 502
#define RAD 11
#define OT 32
#define IT 42   // OT + RAD - 1
#define ITP 44  // padded LDS stride

__global__ __launch_bounds__(256) void ssim_tile_kernel(
    const float* __restrict__ img1, const float* __restrict__ img2,
    const float* __restrict__ win, double* __restrict__ acc)
{
    __shared__ float s1[IT][ITP];
    __shared__ float s2[IT][ITP];
    __shared__ float hM1[IT][OT];
    __shared__ float hM2[IT][OT];
    __shared__ float h11[IT][OT];
    __shared__ float h22[IT][OT];
    __shared__ float h12[IT][OT];
    __shared__ float wsum[4];

    const int tid = threadIdx.x;
    const int tile_c0 = blockIdx.x * OT;
    const int tile_r0 = blockIdx.y * OT;
    const size_t base = (size_t)blockIdx.z * HH * WW;

    // 1-D gaussian weights, reconstructed from the (separable) 2-D window:
    // win[5][j] = g5 * gj, g5 = sqrt(win[5][5])
    float g[RAD];
    {
        double g5 = sqrt((double)win[5 * RAD + 5]);
        #pragma unroll
        for (int k = 0; k < RAD; ++k)
            g[k] = (float)((double)win[5 * RAD + k] / g5);
    }

    // ---- load input tiles (guarded at image edge) ----
    for (int i = tid; i < IT * IT; i += 256) {
        int r = i / IT, c = i % IT;
        int gr = tile_r0 + r, gc = tile_c0 + c;
        float a = 0.f, b = 0.f;
        if (gr < HH && gc < WW) {
            size_t off = base + (size_t)gr * WW + gc;
            a = img1[off];
            b = img2[off];
        }
        s1[r][c] = a;
        s2[r][c] = b;
    }
    __syncthreads();

    // ---- horizontal separable pass: 5 derived channels ----
    for (int i = tid; i < IT * OT; i += 256) {
        int r = i / OT, c = i % OT;
        float m1 = 0.f, m2 = 0.f, p11 = 0.f, p22 = 0.f, p12 = 0.f;
        #pragma unroll
        for (int k = 0; k < RAD; ++k) {
            float a = s1[r][c + k];
            float b = s2[r][c + k];
            float w = g[k];
            m1  += w * a;
            m2  += w * b;
            p11 += w * a * a;
            p22 += w * b * b;
            p12 += w * a * b;
        }
        hM1[r][c] = m1; hM2[r][c] = m2;
        h11[r][c] = p11; h22[r][c] = p22; h12[r][c] = p12;
    }
    __syncthreads();

    // ---- vertical pass + SSIM + accumulate ----
    const float c1 = 1e-4f, c2 = 9e-4f;  // L = 1 for uniform [0,1) inputs
    float lsum = 0.f;
    for (int i = tid; i < OT * OT; i += 256) {
        int r = i / OT, c = i % OT;
        int orr = tile_r0 + r, occ = tile_c0 + c;
        if (orr < HO && occ < WO) {
            float mu1 = 0.f, mu2 = 0.f, e11 = 0.f, e22 = 0.f, e12 = 0.f;
            #pragma unroll
            for (int k = 0; k < RAD; ++k) {
                float w = g[k];
                mu1 += w * hM1[r + k][c];
                mu2 += w * hM2[r + k][c];
                e11 += w * h11[r + k][c];
                e22 += w * h22[r + k][c];
                e12 += w * h12[r + k][c];
            }
            float mu1s = mu1 * mu1, mu2s = mu2 * mu2, mu12 = mu1 * mu2;
            float sg1 = e11 - mu1s, sg2 = e22 - mu2s, sg12 = e12 - mu12;
            float num = (2.f * mu12 + c1) * (2.f * sg12 + c2);
            float den = (mu1s + mu2s + c1) * (sg1 + sg2 + c2);
            lsum += num / den;
        }
    }

    // wave reduce (64 lanes)
    #pragma unroll
    for (int off = 32; off; off >>= 1)
        lsum += __shfl_down(lsum, off, 64);
    int lane = tid & 63, wid = tid >> 6;
    if (lane == 0) wsum[wid] = lsum;
    __syncthreads();
    if (tid == 0) {
        double t = (double)wsum[0] + (double)wsum[1] +
                   (double)wsum[2] + (double)wsum[3];
        atomicAdd(acc, t);
    }
}

__global__ void ssim_finalize(const double* __restrict__ acc,
                              float* __restrict__ out)
{
    out[0] = (float)(acc[0] / (double)(16LL * 3LL * 502LL * 502LL));
}

extern "C" void kernel_launch(void* const* d_in, const int* in_sizes, int n_in,
                              void* d_out, int out_size, void* d_ws, size_t ws_size,
                              hipStream_t stream) {
    const float* img1 = (const float*)d_in[0];
    const float* img2 = (const float*)d_in[1];
    const float* win  = (const float*)d_in[2];  // (3,1,11,11); all channels identical
    float* out = (float*)d_out;
    double* acc = (double*)d_ws;

    hipMemsetAsync(acc, 0, sizeof(double), stream);

    dim3 grid((WO + OT - 1) / OT, (HO + OT - 1) / OT, 16 * 3);
    ssim_tile_kernel<<<grid, 256, 0, stream>>>(img1, img2, win, acc);
    ssim_finalize<<<1, 1, 0, stream>>>(acc, out);
}

// Round 2
// 130.741 us; speedup vs baseline: 1.3671x; 1.3671x over previous
//
#include <hip/hip_runtime.h>

#define HH 512
#define WW 512
#define HO 502
#define WO 502
#define KS 11
#define OTH 32      // output tile rows
#define OTW 54      // output tile cols (v-width = OTW + 10 = 64)
#define VW 64       // v-buffer width
#define RPT 8       // v-rows per thread (phase 1)

// swizzled float index into vbuf[5][OTH][VW]:
// XOR the 8-float slot with (row & 7) -> phase-2 column-slice reads spread banks
__device__ __forceinline__ int vidx(int ch, int r, int c) {
    return ((ch * OTH + r) << 6) + ((((c >> 3) ^ (r & 7)) << 3) | (c & 7));
}

__global__ __launch_bounds__(256, 4) void ssim_sep_kernel(
    const float* __restrict__ img1, const float* __restrict__ img2,
    const float* __restrict__ win, double* __restrict__ acc)
{
    __shared__ float vbuf[5 * OTH * VW];   // 40960 B exactly

    const int tid = threadIdx.x;
    const int tile_c0 = blockIdx.x * OTW;
    const int tile_r0 = blockIdx.y * OTH;
    const size_t base = (size_t)blockIdx.z * (HH * WW);

    // 1-D gaussian reconstructed from separable 2-D window: g[k] = w[5][k]/sqrt(w[5][5])
    float g[KS];
    {
        double g5 = sqrt((double)win[5 * KS + 5]);
        #pragma unroll
        for (int k = 0; k < KS; ++k)
            g[k] = (float)((double)win[5 * KS + k] / g5);
    }

    // ---------- phase 1: vertical conv, global -> registers -> LDS ----------
    {
        const int lane = tid & 63;           // column within v tile
        const int rg = tid >> 6;             // row group 0..3
        const int j0 = rg * RPT;             // first v-row owned
        const int gc = tile_c0 + lane;
        const bool cok = (gc < WW);

        float accv[5][RPT];
        #pragma unroll
        for (int ch = 0; ch < 5; ++ch)
            #pragma unroll
            for (int j = 0; j < RPT; ++j) accv[ch][j] = 0.f;

        #pragma unroll
        for (int ri = 0; ri < RPT + KS - 1; ++ri) {   // 18 input rows
            int gr = tile_r0 + j0 + ri;
            float a = 0.f, b = 0.f;
            if (cok && gr < HH) {
                size_t off = base + (size_t)gr * WW + gc;
                a = img1[off];
                b = img2[off];
            }
            float paa = a * a, pbb = b * b, pab = a * b;
            #pragma unroll
            for (int j = 0; j < RPT; ++j) {
                int k = ri - j;
                if (k >= 0 && k < KS) {        // folds at compile time (full unroll)
                    float w = g[k];
                    accv[0][j] += w * a;
                    accv[1][j] += w * b;
                    accv[2][j] += w * paa;
                    accv[3][j] += w * pbb;
                    accv[4][j] += w * pab;
                }
            }
        }
        #pragma unroll
        for (int ch = 0; ch < 5; ++ch)
            #pragma unroll
            for (int j = 0; j < RPT; ++j)
                vbuf[vidx(ch, j0 + j, lane)] = accv[ch][j];
    }
    __syncthreads();

    // ---------- phase 2: horizontal conv + SSIM, register sliding ----------
    float lsum = 0.f;
    if (tid < 224) {
        const int r  = tid & 31;             // v-row / output row
        const int cg = tid >> 5;             // 0..6, 8 output cols each
        const int c0 = cg * 8;

        float acco[5][8];
        #pragma unroll
        for (int ch = 0; ch < 5; ++ch)
            #pragma unroll
            for (int j = 0; j < 8; ++j) acco[ch][j] = 0.f;

        #pragma unroll
        for (int ch = 0; ch < 5; ++ch) {
            float f[20];
            #pragma unroll
            for (int q = 0; q < 5; ++q) {
                int foff = c0 + q * 4;
                int slot = foff >> 3;
                int idx = ((ch * OTH + r) << 6) +
                          (((slot ^ (r & 7)) << 3) | (foff & 7));
                float4 v4 = *reinterpret_cast<const float4*>(&vbuf[idx]);
                f[q * 4 + 0] = v4.x; f[q * 4 + 1] = v4.y;
                f[q * 4 + 2] = v4.z; f[q * 4 + 3] = v4.w;
            }
            #pragma unroll
            for (int i = 0; i < 18; ++i) {
                #pragma unroll
                for (int j = 0; j < 8; ++j) {
                    int k = i - j;
                    if (k >= 0 && k < KS)
                        acco[ch][j] += g[k] * f[i];
                }
            }
        }

        const float c1 = 1e-4f, c2 = 9e-4f;  // L = 1 for [0,1) inputs
        #pragma unroll
        for (int j = 0; j < 8; ++j) {
            int lc = c0 + j;
            int orow = tile_r0 + r, ocol = tile_c0 + lc;
            if (lc < OTW && orow < HO && ocol < WO) {
                float mu1 = acco[0][j], mu2 = acco[1][j];
                float e11 = acco[2][j], e22 = acco[3][j], e12 = acco[4][j];
                float mu1s = mu1 * mu1, mu2s = mu2 * mu2, mu12 = mu1 * mu2;
                float sg1 = e11 - mu1s, sg2 = e22 - mu2s, sg12 = e12 - mu12;
                float num = (2.f * mu12 + c1) * (2.f * sg12 + c2);
                float den = (mu1s + mu2s + c1) * (sg1 + sg2 + c2);
                lsum += num / den;
            }
        }
    }

    // ---------- reduction ----------
    #pragma unroll
    for (int off = 32; off; off >>= 1)
        lsum += __shfl_down(lsum, off, 64);
    __syncthreads();                          // all vbuf reads done -> reuse for wsum
    if ((tid & 63) == 0) vbuf[tid >> 6] = lsum;
    __syncthreads();
    if (tid == 0) {
        double t = (double)vbuf[0] + (double)vbuf[1] +
                   (double)vbuf[2] + (double)vbuf[3];
        atomicAdd(acc, t);
    }
}

__global__ void ssim_finalize(const double* __restrict__ acc,
                              float* __restrict__ out)
{
    out[0] = (float)(acc[0] / (double)(16LL * 3LL * (long long)HO * (long long)WO));
}

extern "C" void kernel_launch(void* const* d_in, const int* in_sizes, int n_in,
                              void* d_out, int out_size, void* d_ws, size_t ws_size,
                              hipStream_t stream) {
    const float* img1 = (const float*)d_in[0];
    const float* img2 = (const float*)d_in[1];
    const float* win  = (const float*)d_in[2];  // (3,1,11,11); channels identical
    float* out = (float*)d_out;
    double* acc = (double*)d_ws;

    hipMemsetAsync(acc, 0, sizeof(double), stream);

    dim3 grid((WO + OTW - 1) / OTW, (HO + OTH - 1) / OTH, 16 * 3);
    ssim_sep_kernel<<<grid, 256, 0, stream>>>(img1, img2, win, acc);
    ssim_finalize<<<1, 1, 0, stream>>>(acc, out);
}

// Round 3
// 118.988 us; speedup vs baseline: 1.5022x; 1.0988x over previous
//
#include <hip/hip_runtime.h>

#define HH 512
#define WW 512
#define HO 502
#define WO 502
#define KS 11
#define OTH 32                 // output tile rows
#define RPT 8                  // v-rows per thread in phase 1 (4 groups)
#define OTW 52                 // output tile cols
#define VW  62                 // v-buffer cols = OTW + KS - 1
#define RS  33                 // padded row-stride (dwords) per column
#define CHS (VW * RS)          // 2046 dwords per channel
#define CPT 7                  // output cols per thread in phase 2

// symmetric gaussian lookup, k compile-time
#define GW(k) g[(k) < 6 ? (k) : 10 - (k)]

__global__ __launch_bounds__(256) void ssim_sep_kernel(
    const float* __restrict__ img1, const float* __restrict__ img2,
    const float* __restrict__ win, double* __restrict__ acc)
{
    __shared__ float vbuf[5 * CHS];   // 40,920 B -> 4 blocks/CU

    const int tid = threadIdx.x;
    const int tile_c0 = blockIdx.x * OTW;
    const int tile_r0 = blockIdx.y * OTH;
    const size_t base = (size_t)blockIdx.z * (HH * WW);

    // 1-D gaussian from separable 2-D window: g[k] = w[5][k]/sqrt(w[5][5]); symmetric
    float g[6];
    {
        double inv = 1.0 / sqrt((double)win[5 * KS + 5]);
        #pragma unroll
        for (int k = 0; k < 6; ++k)
            g[k] = (float)((double)win[5 * KS + k] * inv);
    }

    // ---------- phase 1: vertical conv, global -> registers -> LDS (transposed) ----------
    {
        const int lane = tid & 63;          // column within v tile
        const int j0 = (tid >> 6) * RPT;    // first v-row owned
        int gc = tile_c0 + lane;
        if (gc > WW - 1) gc = WW - 1;       // clamped cols only feed discarded outputs

        float accv[5][RPT];
        #pragma unroll
        for (int ch = 0; ch < 5; ++ch)
            #pragma unroll
            for (int j = 0; j < RPT; ++j) accv[ch][j] = 0.f;

        const float* p1 = img1 + base + gc;
        const float* p2 = img2 + base + gc;
        #pragma unroll
        for (int ri = 0; ri < RPT + KS - 1; ++ri) {   // 18 input rows
            int gr = tile_r0 + j0 + ri;
            if (gr > HH - 1) gr = HH - 1;             // clamped rows feed discarded outputs
            float a = p1[(size_t)gr * WW];
            float b = p2[(size_t)gr * WW];
            float aa = a * a, bb = b * b, ab = a * b;
            #pragma unroll
            for (int j = 0; j < RPT; ++j) {
                int k = ri - j;
                if (k >= 0 && k < KS) {               // folds at compile time
                    float w = GW(k);
                    accv[0][j] += w * a;
                    accv[1][j] += w * b;
                    accv[2][j] += w * aa;
                    accv[3][j] += w * bb;
                    accv[4][j] += w * ab;
                }
            }
        }
        if (lane < VW) {
            const int cb = lane * RS + j0;
            #pragma unroll
            for (int ch = 0; ch < 5; ++ch)
                #pragma unroll
                for (int j = 0; j < RPT; ++j)
                    vbuf[ch * CHS + cb + j] = accv[ch][j];
        }
    }
    __syncthreads();

    // ---------- phase 2: horizontal conv + SSIM ----------
    float lsum = 0.f;
    {
        const int r  = tid & 31;            // output row in tile
        const int c0 = (tid >> 5) * CPT;    // first output col (0..49)

        float acco[5][CPT];
        #pragma unroll
        for (int ch = 0; ch < 5; ++ch)
            #pragma unroll
            for (int j = 0; j < CPT; ++j) acco[ch][j] = 0.f;

        #pragma unroll
        for (int ch = 0; ch < 5; ++ch) {
            const float* vp = &vbuf[ch * CHS + r];
            #pragma unroll
            for (int i = 0; i < CPT + KS - 1; ++i) {  // 17 positions
                int ci = c0 + i;
                if (i >= 13) ci = (ci > VW - 1) ? VW - 1 : ci;  // only last col-group
                float v = vp[ci * RS];                // lanes r=0..31 -> consecutive addrs
                #pragma unroll
                for (int j = 0; j < CPT; ++j) {
                    int k = i - j;
                    if (k >= 0 && k < KS)             // folds at compile time
                        acco[ch][j] += GW(k) * v;
                }
            }
        }

        const float c1 = 1e-4f, c2 = 9e-4f;           // L = 1 for [0,1) inputs
        const int orow = tile_r0 + r;
        #pragma unroll
        for (int j = 0; j < CPT; ++j) {
            int lc = c0 + j, ocol = tile_c0 + lc;
            if (lc < OTW && ocol < WO && orow < HO) {
                float mu1 = acco[0][j], mu2 = acco[1][j];
                float e11 = acco[2][j], e22 = acco[3][j], e12 = acco[4][j];
                float mu1s = mu1 * mu1, mu2s = mu2 * mu2, mu12 = mu1 * mu2;
                float sg1 = e11 - mu1s, sg2 = e22 - mu2s, sg12 = e12 - mu12;
                float num = (2.f * mu12 + c1) * (2.f * sg12 + c2);
                float den = (mu1s + mu2s + c1) * (sg1 + sg2 + c2);
                lsum += num * __builtin_amdgcn_rcpf(den);
            }
        }
    }

    // ---------- reduction ----------
    #pragma unroll
    for (int off = 32; off; off >>= 1)
        lsum += __shfl_down(lsum, off, 64);
    __syncthreads();                      // vbuf reads done -> reuse for partials
    if ((tid & 63) == 0) vbuf[tid >> 6] = lsum;
    __syncthreads();
    if (tid == 0) {
        double t = (double)vbuf[0] + (double)vbuf[1] +
                   (double)vbuf[2] + (double)vbuf[3];
        atomicAdd(acc, t);
    }
}

__global__ void ssim_finalize(const double* __restrict__ acc,
                              float* __restrict__ out)
{
    out[0] = (float)(acc[0] / (double)(16LL * 3LL * (long long)HO * (long long)WO));
}

extern "C" void kernel_launch(void* const* d_in, const int* in_sizes, int n_in,
                              void* d_out, int out_size, void* d_ws, size_t ws_size,
                              hipStream_t stream) {
    const float* img1 = (const float*)d_in[0];
    const float* img2 = (const float*)d_in[1];
    const float* win  = (const float*)d_in[2];  // (3,1,11,11); channels identical
    float* out = (float*)d_out;
    double* acc = (double*)d_ws;

    hipMemsetAsync(acc, 0, sizeof(double), stream);

    dim3 grid((WO + OTW - 1) / OTW, (HO + OTH - 1) / OTH, 16 * 3);
    ssim_sep_kernel<<<grid, 256, 0, stream>>>(img1, img2, win, acc);
    ssim_finalize<<<1, 1, 0, stream>>>(acc, out);
}